// Round 6
// baseline (264.612 us; speedup 1.0000x reference)
//
#include <hip/hip_runtime.h>

#define NEG_W 8.0f
#define EPS 1e-7f
#define TPB 256
#define VPT 8                 // 8 float4 + 8 int4 per thread
#define BLOCKS 4096           // 4096*256*8 float4 = 8,388,608 = N/4 exactly

typedef float f32x4 __attribute__((ext_vector_type(4)));
typedef int   i32x4 __attribute__((ext_vector_type(4)));

// Round 8. Ladder: 97us (r0, non-nt, L3-hit path cap 2.7 TB/s) -> 73us (r6,
// nt both streams, 3.7 TB/s) -> 69us (r7, VPT=8, marginal: VPT scales
// in-flight bytes AND compute together, duty cycle unchanged -> concurrency
// is not the limiter). Fill kernels prove 6.9 TB/s one-way (write) is
// sustainable. New theory: TWO separable ingress paths -- L3-lookup path
// (~2.7 TB/s, backing-store-agnostic per r0 replay evidence) and nt/HBM
// path (~3.9 TB/s). Split streams across them: targets (128 MB, fits L3
// entirely across replay iterations) via NORMAL loads; outputs via nt.
//   parallel paths  -> ~47-55us, FETCH halves to ~135 GB-KB
//   serialized path -> null, declare read-path roofline next round
__global__ __launch_bounds__(TPB) void bce_partial(
    const f32x4* __restrict__ out4, const i32x4* __restrict__ tgt4,
    float* __restrict__ partials) {
  const int base = blockIdx.x * (TPB * VPT) + threadIdx.x;

  f32x4 o[VPT];
  i32x4 t[VPT];
#pragma unroll
  for (int u = 0; u < VPT; ++u) {
    const int idx = base + u * TPB;   // coalesced within each unroll slot
    o[u] = __builtin_nontemporal_load(out4 + idx);  // nt: stream from HBM
    t[u] = tgt4[idx];                               // normal: L3-resident
  }
  __builtin_amdgcn_sched_barrier(0);  // keep the 16-load burst clustered

  float acc0 = 0.0f, acc1 = 0.0f, acc2 = 0.0f, acc3 = 0.0f;
#pragma unroll
  for (int u = 0; u < VPT; ++u) {
    float x0 = (t[u].x == 1) ? (o[u].x + EPS) : (1.0f - o[u].x + EPS);
    float w0 = (t[u].x == 1) ? 1.0f : NEG_W;
    float x1 = (t[u].y == 1) ? (o[u].y + EPS) : (1.0f - o[u].y + EPS);
    float w1 = (t[u].y == 1) ? 1.0f : NEG_W;
    float x2 = (t[u].z == 1) ? (o[u].z + EPS) : (1.0f - o[u].z + EPS);
    float w2 = (t[u].z == 1) ? 1.0f : NEG_W;
    float x3 = (t[u].w == 1) ? (o[u].w + EPS) : (1.0f - o[u].w + EPS);
    float w3 = (t[u].w == 1) ? 1.0f : NEG_W;
    acc0 = fmaf(w0, __logf(x0), acc0);
    acc1 = fmaf(w1, __logf(x1), acc1);
    acc2 = fmaf(w2, __logf(x2), acc2);
    acc3 = fmaf(w3, __logf(x3), acc3);
  }
  float sum = -((acc0 + acc1) + (acc2 + acc3));

  // wave64 butterfly reduce
  for (int off = 32; off > 0; off >>= 1)
    sum += __shfl_down(sum, off, 64);

  __shared__ float wsum[TPB / 64];
  const int lane = threadIdx.x & 63;
  const int wid = threadIdx.x >> 6;
  if (lane == 0) wsum[wid] = sum;
  __syncthreads();
  if (threadIdx.x == 0) {
    float s = 0.0f;
    for (int w = 0; w < TPB / 64; ++w) s += wsum[w];
    partials[blockIdx.x] = s;
  }
}

// Kernel 2: single block reduces BLOCKS float partials in double, writes mean.
__global__ __launch_bounds__(TPB) void bce_finalize(
    const float* __restrict__ partials, float* __restrict__ out, int nblocks,
    double inv_n) {
  double s = 0.0;
  for (int i = threadIdx.x; i < nblocks; i += TPB) s += (double)partials[i];
  for (int off = 32; off > 0; off >>= 1)
    s += __shfl_down(s, off, 64);
  __shared__ double wsum[TPB / 64];
  const int lane = threadIdx.x & 63;
  const int wid = threadIdx.x >> 6;
  if (lane == 0) wsum[wid] = s;
  __syncthreads();
  if (threadIdx.x == 0) {
    double tot = 0.0;
    for (int w = 0; w < TPB / 64; ++w) tot += wsum[w];
    out[0] = (float)(tot * inv_n);
  }
}

extern "C" void kernel_launch(void* const* d_in, const int* in_sizes, int n_in,
                              void* d_out, int out_size, void* d_ws, size_t ws_size,
                              hipStream_t stream) {
  const f32x4* out4 = (const f32x4*)d_in[0];
  const i32x4* tgt4 = (const i32x4*)d_in[1];
  const int n = in_sizes[0];          // 33554432 = BLOCKS*TPB*VPT*4 exactly
  float* partials = (float*)d_ws;     // 4096 * 4 B = 16 KB scratch
  (void)n;

  bce_partial<<<BLOCKS, TPB, 0, stream>>>(out4, tgt4, partials);
  bce_finalize<<<1, TPB, 0, stream>>>(partials, (float*)d_out, BLOCKS,
                                      1.0 / (double)33554432);
}